// Round 2
// baseline (438.258 us; speedup 1.0000x reference)
//
#include <hip/hip_runtime.h>
#include <hip/hip_bf16.h>

typedef __attribute__((ext_vector_type(8))) _Float16 half8;
typedef __attribute__((ext_vector_type(2))) _Float16 half2v;
typedef __attribute__((ext_vector_type(4))) float f32x4;

#define N_NODES 100000
#define N_EDGES 1600000
#define IN_CH 1024
#define FEAT 128

__global__ void k_zero(int* __restrict__ p, int n) {
    int i = blockIdx.x * 256 + threadIdx.x;
    if (i < n) p[i] = 0;
}

__global__ void k_count(const int* __restrict__ dst, int* __restrict__ cnt, int e) {
    int i = blockIdx.x * 256 + threadIdx.x;
    if (i >= e) return;
    unsigned d = (unsigned)dst[i];
    if (d < N_NODES) atomicAdd(&cnt[d], 1);
}

// exclusive scan over cnt[0..n), 1024 elems per block (256 thr x 4)
__global__ void k_scanA(const int* __restrict__ cnt, int* __restrict__ off,
                        int* __restrict__ bsum, int n) {
    __shared__ int sd[256];
    int t = threadIdx.x, b = blockIdx.x;
    int base = b * 1024 + t * 4;
    int v[4]; int tsum = 0;
#pragma unroll
    for (int j = 0; j < 4; ++j) { int idx = base + j; v[j] = (idx < n) ? cnt[idx] : 0; tsum += v[j]; }
    sd[t] = tsum; __syncthreads();
    for (int d = 1; d < 256; d <<= 1) {
        int y = (t >= d) ? sd[t - d] : 0;
        __syncthreads();
        sd[t] += y;
        __syncthreads();
    }
    int run = sd[t] - tsum;   // exclusive within block
#pragma unroll
    for (int j = 0; j < 4; ++j) { int idx = base + j; if (idx < n) off[idx] = run; run += v[j]; }
    if (t == 255) bsum[b] = sd[255];
}

__global__ void k_scanB(const int* __restrict__ bsum, int* __restrict__ bsum2, int nb) {
    __shared__ int sd[128];
    int t = threadIdx.x;
    int v = (t < nb) ? bsum[t] : 0;
    sd[t] = v; __syncthreads();
    for (int d = 1; d < 128; d <<= 1) {
        int y = (t >= d) ? sd[t - d] : 0;
        __syncthreads();
        sd[t] += y;
        __syncthreads();
    }
    if (t < nb) bsum2[t] = sd[t] - v;
}

__global__ void k_scanC(int* __restrict__ off, const int* __restrict__ bsum2,
                        const int* __restrict__ cnt, int* __restrict__ cursor,
                        float* __restrict__ dinv, int n) {
    int t = threadIdx.x, b = blockIdx.x;
    int add = bsum2[b];
    int base = b * 1024 + t * 4;
#pragma unroll
    for (int j = 0; j < 4; ++j) {
        int idx = base + j;
        if (idx < n) {
            int o = off[idx] + add;
            off[idx] = o;
            cursor[idx] = o;
            dinv[idx] = rsqrtf((float)(cnt[idx] + 1));
        }
    }
}

__global__ void k_fill(const int* __restrict__ src, const int* __restrict__ dst,
                       int* __restrict__ cursor, int* __restrict__ csr, int e) {
    int i = blockIdx.x * 256 + threadIdx.x;
    if (i >= e) return;
    unsigned d = (unsigned)dst[i];
    unsigned s = (unsigned)src[i];
    if (d >= N_NODES || s >= N_NODES) return;
    int p = atomicAdd(&cursor[d], 1);
    csr[p] = (int)s;
}

// W1t[col][k] = (fp16) W1[k][col]
__global__ void k_w1cvt(const float* __restrict__ W1, _Float16* __restrict__ W1t) {
    int idx = blockIdx.x * 256 + threadIdx.x;
    if (idx < IN_CH * FEAT) {
        int col = idx & (FEAT - 1);
        int k = idx >> 7;
        W1t[(size_t)col * IN_CH + k] = (_Float16)W1[idx];
    }
}

// H = features @ W1 (fp16 MFMA, f32 acc), H stored fp16 row-major [N][128]
__global__ __launch_bounds__(256) void k_gemm1(const float* __restrict__ A,
                                               const _Float16* __restrict__ Bt,
                                               _Float16* __restrict__ H, int M) {
    __shared__ _Float16 As[128][72];   // padded: stride 144B -> 2-way (free) bank alias
    __shared__ _Float16 Bs[128][72];   // Bs[col][k]
    int t = threadIdx.x;
    int wid = t >> 6, lane = t & 63;
    int brow0 = blockIdx.x * 128;

    f32x4 acc[2][8];
#pragma unroll
    for (int m = 0; m < 2; ++m)
#pragma unroll
        for (int nn = 0; nn < 8; ++nn) acc[m][nn] = (f32x4){0.f, 0.f, 0.f, 0.f};

    int srow = t >> 2;
    int skoff = (t & 3) << 4;
    int bcol = t >> 1;
    int bkoff = (t & 1) << 5;

    for (int kt = 0; kt < IN_CH / 64; ++kt) {
        // stage A: 128 rows x 64 k f32 -> fp16
#pragma unroll
        for (int cc = 0; cc < 2; ++cc) {
            int row = srow + cc * 64;
            int grow = brow0 + row; if (grow >= M) grow = M - 1;
            const float4* s4 = (const float4*)(A + (size_t)grow * IN_CH + kt * 64 + skoff);
            float4 f0 = s4[0], f1 = s4[1], f2 = s4[2], f3 = s4[3];
            half8 h0, h1;
            h0[0] = (_Float16)f0.x; h0[1] = (_Float16)f0.y; h0[2] = (_Float16)f0.z; h0[3] = (_Float16)f0.w;
            h0[4] = (_Float16)f1.x; h0[5] = (_Float16)f1.y; h0[6] = (_Float16)f1.z; h0[7] = (_Float16)f1.w;
            h1[0] = (_Float16)f2.x; h1[1] = (_Float16)f2.y; h1[2] = (_Float16)f2.z; h1[3] = (_Float16)f2.w;
            h1[4] = (_Float16)f3.x; h1[5] = (_Float16)f3.y; h1[6] = (_Float16)f3.z; h1[7] = (_Float16)f3.w;
            *(half8*)(&As[row][skoff]) = h0;
            *(half8*)(&As[row][skoff + 8]) = h1;
        }
        // stage B: 128 cols x 64 k fp16 (already fp16 in Bt)
        {
            const half8* src = (const half8*)(Bt + (size_t)bcol * IN_CH + kt * 64 + bkoff);
#pragma unroll
            for (int j = 0; j < 4; ++j) *(half8*)(&Bs[bcol][bkoff + j * 8]) = src[j];
        }
        __syncthreads();
#pragma unroll
        for (int kk = 0; kk < 2; ++kk) {
            int ko = kk * 32 + (lane >> 4) * 8;
            half8 a0 = *(const half8*)(&As[wid * 32 + (lane & 15)][ko]);
            half8 a1 = *(const half8*)(&As[wid * 32 + 16 + (lane & 15)][ko]);
#pragma unroll
            for (int nn = 0; nn < 8; ++nn) {
                half8 b = *(const half8*)(&Bs[nn * 16 + (lane & 15)][ko]);
                acc[0][nn] = __builtin_amdgcn_mfma_f32_16x16x32_f16(a0, b, acc[0][nn], 0, 0, 0);
                acc[1][nn] = __builtin_amdgcn_mfma_f32_16x16x32_f16(a1, b, acc[1][nn], 0, 0, 0);
            }
        }
        __syncthreads();
    }
    // epilogue: C/D layout col=lane&15, row=(lane>>4)*4+r
    int colb = lane & 15, rgrp = (lane >> 4) * 4;
#pragma unroll
    for (int m = 0; m < 2; ++m) {
#pragma unroll
        for (int r = 0; r < 4; ++r) {
            int grow = brow0 + wid * 32 + m * 16 + rgrp + r;
            if (grow < M) {
                _Float16* hp = H + (size_t)grow * FEAT + colb;
#pragma unroll
                for (int nn = 0; nn < 8; ++nn) hp[nn * 16] = (_Float16)acc[m][nn][r];
            }
        }
    }
}

// agg1 + bias + relu + @W2 : one wave per node, lane owns channels {2l, 2l+1}
__global__ __launch_bounds__(256) void k_agg1(const _Float16* __restrict__ H,
                                              const int* __restrict__ csr,
                                              const int* __restrict__ off,
                                              const int* __restrict__ cnt,
                                              const float* __restrict__ dinv,
                                              const float* __restrict__ b1,
                                              const float* __restrict__ W2,
                                              float* __restrict__ Y, int n) {
    int wid = threadIdx.x >> 6, lane = threadIdx.x & 63;
    int i = blockIdx.x * 4 + wid;
    if (i >= n) return;
    int base = off[i], m = cnt[i];
    float di = dinv[i];
    int c0 = lane * 2;
    float ax = 0.f, ay = 0.f;
    int mm = m < 64 ? m : 64;
    int sl = 0; float dl = 0.f;
    if (lane < mm) { sl = csr[base + lane]; dl = dinv[sl]; }
    int e = 0;
    for (; e + 1 < mm; e += 2) {
        int s0 = __shfl(sl, e), s1 = __shfl(sl, e + 1);
        float d0 = __shfl(dl, e), d1 = __shfl(dl, e + 1);
        half2v h0 = *(const half2v*)(H + (size_t)s0 * FEAT + c0);
        half2v h1 = *(const half2v*)(H + (size_t)s1 * FEAT + c0);
        ax += d0 * (float)h0[0] + d1 * (float)h1[0];
        ay += d0 * (float)h0[1] + d1 * (float)h1[1];
    }
    if (e < mm) {
        int s0 = __shfl(sl, e); float d0 = __shfl(dl, e);
        half2v h0 = *(const half2v*)(H + (size_t)s0 * FEAT + c0);
        ax += d0 * (float)h0[0];
        ay += d0 * (float)h0[1];
        ++e;
    }
    for (; e < m; ++e) {  // degree > 64 fallback (rare)
        int s0 = csr[base + e]; float d0 = dinv[s0];
        half2v h0 = *(const half2v*)(H + (size_t)s0 * FEAT + c0);
        ax += d0 * (float)h0[0];
        ay += d0 * (float)h0[1];
    }
    {   // self loop
        half2v hs = *(const half2v*)(H + (size_t)i * FEAT + c0);
        ax += di * (float)hs[0];
        ay += di * (float)hs[1];
    }
    float x0 = di * ax + b1[c0];     x0 = x0 > 0.f ? x0 : 0.f;
    float x1 = di * ay + b1[c0 + 1]; x1 = x1 > 0.f ? x1 : 0.f;
    // project to 3 channels: W2 is [128][3] row-major
    float y0 = x0 * W2[c0 * 3 + 0] + x1 * W2[c0 * 3 + 3];
    float y1 = x0 * W2[c0 * 3 + 1] + x1 * W2[c0 * 3 + 4];
    float y2 = x0 * W2[c0 * 3 + 2] + x1 * W2[c0 * 3 + 5];
#pragma unroll
    for (int d = 1; d < 64; d <<= 1) {
        y0 += __shfl_xor(y0, d);
        y1 += __shfl_xor(y1, d);
        y2 += __shfl_xor(y2, d);
    }
    if (lane == 0) {
        float* yp = Y + (size_t)i * 4;
        yp[0] = y0; yp[1] = y1; yp[2] = y2;
    }
}

// agg2: thread per node, 3 channels, Y stride 4
__global__ void k_agg2(const float* __restrict__ Y, const int* __restrict__ csr,
                       const int* __restrict__ off, const int* __restrict__ cnt,
                       const float* __restrict__ dinv, const float* __restrict__ b2,
                       float* __restrict__ out, int n) {
    int i = blockIdx.x * 256 + threadIdx.x;
    if (i >= n) return;
    int base = off[i], m = cnt[i];
    float di = dinv[i];
    const float4* Y4 = (const float4*)Y;
    float4 self = Y4[i];
    float a0 = di * self.x, a1 = di * self.y, a2 = di * self.z;
    int e = 0;
    for (; e + 1 < m; e += 2) {
        int s0 = csr[base + e], s1 = csr[base + e + 1];
        float d0 = dinv[s0], d1 = dinv[s1];
        float4 v0 = Y4[s0], v1 = Y4[s1];
        a0 += d0 * v0.x + d1 * v1.x;
        a1 += d0 * v0.y + d1 * v1.y;
        a2 += d0 * v0.z + d1 * v1.z;
    }
    if (e < m) {
        int s0 = csr[base + e]; float d0 = dinv[s0]; float4 v0 = Y4[s0];
        a0 += d0 * v0.x; a1 += d0 * v0.y; a2 += d0 * v0.z;
    }
    out[(size_t)i * 3 + 0] = di * a0 + b2[0];
    out[(size_t)i * 3 + 1] = di * a1 + b2[1];
    out[(size_t)i * 3 + 2] = di * a2 + b2[2];
}

extern "C" void kernel_launch(void* const* d_in, const int* in_sizes, int n_in,
                              void* d_out, int out_size, void* d_ws, size_t ws_size,
                              hipStream_t stream) {
    const float* features = (const float*)d_in[0];
    const int* edges2 = (const int*)d_in[2];   // int64 in reference -> int32 on device
    const float* W1 = (const float*)d_in[5];
    const float* b1 = (const float*)d_in[6];
    const float* W2 = (const float*)d_in[7];
    const float* b2 = (const float*)d_in[8];
    float* out = (float*)d_out;

    const int N = N_NODES, E = N_EDGES;
    const int* srcp = edges2;
    const int* dstp = edges2 + E;

    char* p = (char*)d_ws;
    auto carve = [&](size_t bytes) { char* q = p; p += (bytes + 255) & ~(size_t)255; return q; };
    int* cnt      = (int*)carve(4 * (size_t)N);
    int* off      = (int*)carve(4 * (size_t)N);
    int* cursor   = (int*)carve(4 * (size_t)N);
    int* bsum     = (int*)carve(4 * 128);
    int* bsum2    = (int*)carve(4 * 128);
    int* csr      = (int*)carve(4 * (size_t)E);
    float* dinv   = (float*)carve(4 * (size_t)N);
    _Float16* W1t = (_Float16*)carve(2 * (size_t)IN_CH * FEAT);
    _Float16* H   = (_Float16*)carve(2 * (size_t)N * FEAT);
    float* Y      = (float*)carve(16 * (size_t)N);

    int nb = (N + 1023) / 1024;  // 98

    k_zero<<<dim3((N + 255) / 256), dim3(256), 0, stream>>>(cnt, N);
    k_count<<<dim3((E + 255) / 256), dim3(256), 0, stream>>>(dstp, cnt, E);
    k_scanA<<<dim3(nb), dim3(256), 0, stream>>>(cnt, off, bsum, N);
    k_scanB<<<dim3(1), dim3(128), 0, stream>>>(bsum, bsum2, nb);
    k_scanC<<<dim3(nb), dim3(256), 0, stream>>>(off, bsum2, cnt, cursor, dinv, N);
    k_fill<<<dim3((E + 255) / 256), dim3(256), 0, stream>>>(srcp, dstp, cursor, csr, E);
    k_w1cvt<<<dim3((IN_CH * FEAT) / 256), dim3(256), 0, stream>>>(W1, W1t);
    k_gemm1<<<dim3((N + 127) / 128), dim3(256), 0, stream>>>(features, W1t, H, N);
    k_agg1<<<dim3((N + 3) / 4), dim3(256), 0, stream>>>(H, csr, off, cnt, dinv, b1, W2, Y, N);
    k_agg2<<<dim3((N + 255) / 256), dim3(256), 0, stream>>>(Y, csr, off, cnt, dinv, b2, out, N);
}

// Round 3
// 437.607 us; speedup vs baseline: 1.0015x; 1.0015x over previous
//
#include <hip/hip_runtime.h>
#include <hip/hip_bf16.h>

typedef __attribute__((ext_vector_type(8))) _Float16 half8;
typedef __attribute__((ext_vector_type(2))) _Float16 half2v;
typedef __attribute__((ext_vector_type(4))) float f32x4;

#define N_NODES 100000
#define N_EDGES 1600000
#define IN_CH 1024
#define FEAT 128

// fused: zero cnt + convert/transpose W1 -> fp16 [col][k]
__global__ void k_init(const float* __restrict__ W1, _Float16* __restrict__ W1t,
                       int* __restrict__ cnt) {
    int idx = blockIdx.x * 256 + threadIdx.x;
    if (idx < IN_CH * FEAT) {
        int col = idx & (FEAT - 1);
        int k = idx >> 7;
        W1t[(size_t)col * IN_CH + k] = (_Float16)W1[idx];
    }
    if (idx < N_NODES) cnt[idx] = 0;
}

__global__ void k_count(const int4* __restrict__ dst4, int* __restrict__ cnt, int e4) {
    int i = blockIdx.x * 256 + threadIdx.x;
    if (i >= e4) return;
    int4 d = dst4[i];
    if ((unsigned)d.x < N_NODES) atomicAdd(&cnt[d.x], 1);
    if ((unsigned)d.y < N_NODES) atomicAdd(&cnt[d.y], 1);
    if ((unsigned)d.z < N_NODES) atomicAdd(&cnt[d.z], 1);
    if ((unsigned)d.w < N_NODES) atomicAdd(&cnt[d.w], 1);
}

// exclusive scan over cnt[0..n), 1024 elems per block (256 thr x 4)
__global__ void k_scanA(const int* __restrict__ cnt, int* __restrict__ off,
                        int* __restrict__ bsum, int n) {
    __shared__ int sd[256];
    int t = threadIdx.x, b = blockIdx.x;
    int base = b * 1024 + t * 4;
    int v[4]; int tsum = 0;
#pragma unroll
    for (int j = 0; j < 4; ++j) { int idx = base + j; v[j] = (idx < n) ? cnt[idx] : 0; tsum += v[j]; }
    sd[t] = tsum; __syncthreads();
    for (int d = 1; d < 256; d <<= 1) {
        int y = (t >= d) ? sd[t - d] : 0;
        __syncthreads();
        sd[t] += y;
        __syncthreads();
    }
    int run = sd[t] - tsum;
#pragma unroll
    for (int j = 0; j < 4; ++j) { int idx = base + j; if (idx < n) off[idx] = run; run += v[j]; }
    if (t == 255) bsum[b] = sd[255];
}

__global__ void k_scanB(const int* __restrict__ bsum, int* __restrict__ bsum2, int nb) {
    __shared__ int sd[128];
    int t = threadIdx.x;
    int v = (t < nb) ? bsum[t] : 0;
    sd[t] = v; __syncthreads();
    for (int d = 1; d < 128; d <<= 1) {
        int y = (t >= d) ? sd[t - d] : 0;
        __syncthreads();
        sd[t] += y;
        __syncthreads();
    }
    if (t < nb) bsum2[t] = sd[t] - v;
}

__global__ void k_scanC(int* __restrict__ off, const int* __restrict__ bsum2,
                        const int* __restrict__ cnt, int* __restrict__ cursor,
                        float* __restrict__ dinv, int n) {
    int t = threadIdx.x, b = blockIdx.x;
    int add = bsum2[b];
    int base = b * 1024 + t * 4;
#pragma unroll
    for (int j = 0; j < 4; ++j) {
        int idx = base + j;
        if (idx < n) {
            int o = off[idx] + add;
            off[idx] = o;
            cursor[idx] = o;
            dinv[idx] = rsqrtf((float)(cnt[idx] + 1));
        }
    }
}

__global__ void k_fill(const int4* __restrict__ src4, const int4* __restrict__ dst4,
                       int* __restrict__ cursor, int* __restrict__ csr, int e4) {
    int i = blockIdx.x * 256 + threadIdx.x;
    if (i >= e4) return;
    int4 s = src4[i];
    int4 d = dst4[i];
    if ((unsigned)d.x < N_NODES && (unsigned)s.x < N_NODES) csr[atomicAdd(&cursor[d.x], 1)] = s.x;
    if ((unsigned)d.y < N_NODES && (unsigned)s.y < N_NODES) csr[atomicAdd(&cursor[d.y], 1)] = s.y;
    if ((unsigned)d.z < N_NODES && (unsigned)s.z < N_NODES) csr[atomicAdd(&cursor[d.z], 1)] = s.z;
    if ((unsigned)d.w < N_NODES && (unsigned)s.w < N_NODES) csr[atomicAdd(&cursor[d.w], 1)] = s.w;
}

// H = features @ W1.  A direct global->reg (each A row used by exactly one wave,
// each element by exactly one lane fragment -> no A LDS, no A staging VALU).
// B (16 KB/K-step, L2-resident) double-buffered in padded LDS. 1 barrier/K-step.
__global__ __launch_bounds__(256, 2) void k_gemm1(const float* __restrict__ A,
                                                  const _Float16* __restrict__ Bt,
                                                  _Float16* __restrict__ H, int M) {
    __shared__ _Float16 Bs[2][128][72];   // pad 72: stride 144B -> benign aliasing
    const int t = threadIdx.x;
    const int wid = t >> 6, lane = t & 63;
    const int brow0 = blockIdx.x * 128;
    const int NKT = IN_CH / 64;   // 16

    f32x4 acc[2][8];
#pragma unroll
    for (int m = 0; m < 2; ++m)
#pragma unroll
        for (int nn = 0; nn < 8; ++nn) acc[m][nn] = (f32x4){0.f, 0.f, 0.f, 0.f};

    // A fragment addressing (frag(m,kk): row = brow0+wid*32+m*16+(lane&15),
    // k = kt*64 + kk*32 + (lane>>4)*8 + j)
    int r0 = brow0 + wid * 32 + (lane & 15);
    int r1 = r0 + 16;
    if (r0 >= M) r0 = M - 1;
    if (r1 >= M) r1 = M - 1;
    const int kbase = (lane >> 4) * 8;
    const float* pa0 = A + (size_t)r0 * IN_CH + kbase;
    const float* pa1 = A + (size_t)r1 * IN_CH + kbase;

    // B staging: thread t stages col=t>>1, k-range (t&1)*32..+32 (64 B)
    const int bcol = t >> 1;
    const int bko = (t & 1) * 32;
    const _Float16* pb = Bt + (size_t)bcol * IN_CH + bko;

    float4 ar[2][2][2];   // raw f32 A [m][kk][j]
    half8 af[2][2];       // fp16 A fragments
    half8 bst[4];         // B staging regs

#define LOAD_A(kt)                                                              \
    {                                                                           \
        _Pragma("unroll") for (int m = 0; m < 2; ++m) {                         \
            const float* p_ = (m ? pa1 : pa0) + (kt) * 64;                      \
            _Pragma("unroll") for (int kk = 0; kk < 2; ++kk) {                  \
                ar[m][kk][0] = *(const float4*)(p_ + kk * 32);                  \
                ar[m][kk][1] = *(const float4*)(p_ + kk * 32 + 4);              \
            }                                                                   \
        }                                                                       \
    }
#define CVT_A()                                                                 \
    {                                                                           \
        _Pragma("unroll") for (int m = 0; m < 2; ++m)                           \
        _Pragma("unroll") for (int kk = 0; kk < 2; ++kk) {                      \
            half8 h;                                                            \
            h[0] = (_Float16)ar[m][kk][0].x; h[1] = (_Float16)ar[m][kk][0].y;   \
            h[2] = (_Float16)ar[m][kk][0].z; h[3] = (_Float16)ar[m][kk][0].w;   \
            h[4] = (_Float16)ar[m][kk][1].x; h[5] = (_Float16)ar[m][kk][1].y;   \
            h[6] = (_Float16)ar[m][kk][1].z; h[7] = (_Float16)ar[m][kk][1].w;   \
            af[m][kk] = h;                                                      \
        }                                                                       \
    }
#define LOAD_B(kt)                                                              \
    {                                                                           \
        const half8* s_ = (const half8*)(pb + (kt) * 64);                       \
        _Pragma("unroll") for (int j = 0; j < 4; ++j) bst[j] = s_[j];           \
    }
#define WRITE_B(buf)                                                            \
    {                                                                           \
        _Pragma("unroll") for (int j = 0; j < 4; ++j)                           \
            *(half8*)(&Bs[buf][bcol][bko + j * 8]) = bst[j];                    \
    }

    LOAD_A(0); LOAD_B(0);
    CVT_A();
    WRITE_B(0);
    __syncthreads();

    for (int kt = 0; kt < NKT; ++kt) {
        const int cur = kt & 1;
        const bool more = (kt + 1 < NKT);
        if (more) { LOAD_B(kt + 1); LOAD_A(kt + 1); }   // in flight across MFMA
#pragma unroll
        for (int kk = 0; kk < 2; ++kk) {
            half8 a0 = af[0][kk], a1 = af[1][kk];
#pragma unroll
            for (int nn = 0; nn < 8; ++nn) {
                half8 b = *(const half8*)(&Bs[cur][nn * 16 + (lane & 15)][kk * 32 + kbase]);
                acc[0][nn] = __builtin_amdgcn_mfma_f32_16x16x32_f16(a0, b, acc[0][nn], 0, 0, 0);
                acc[1][nn] = __builtin_amdgcn_mfma_f32_16x16x32_f16(a1, b, acc[1][nn], 0, 0, 0);
            }
        }
        if (more) {
            CVT_A();            // waits on A vmcnt, mostly hidden under MFMA
            WRITE_B(cur ^ 1);   // waits on B vmcnt (L2-resident)
            __syncthreads();
        }
    }
#undef LOAD_A
#undef CVT_A
#undef LOAD_B
#undef WRITE_B

    // epilogue: C/D layout col=lane&15, row=(lane>>4)*4+r
    int colb = lane & 15, rgrp = (lane >> 4) * 4;
#pragma unroll
    for (int m = 0; m < 2; ++m) {
#pragma unroll
        for (int r = 0; r < 4; ++r) {
            int grow = brow0 + wid * 32 + m * 16 + rgrp + r;
            if (grow < M) {
                _Float16* hp = H + (size_t)grow * FEAT + colb;
#pragma unroll
                for (int nn = 0; nn < 8; ++nn) hp[nn * 16] = (_Float16)acc[m][nn][r];
            }
        }
    }
}

// agg1 + bias + relu + @W2 : one wave per node, lane owns channels {2l, 2l+1}
__global__ __launch_bounds__(256) void k_agg1(const _Float16* __restrict__ H,
                                              const int* __restrict__ csr,
                                              const int* __restrict__ off,
                                              const int* __restrict__ cnt,
                                              const float* __restrict__ dinv,
                                              const float* __restrict__ b1,
                                              const float* __restrict__ W2,
                                              float* __restrict__ Y, int n) {
    int wid = threadIdx.x >> 6, lane = threadIdx.x & 63;
    int i = blockIdx.x * 4 + wid;
    if (i >= n) return;
    int base = off[i], m = cnt[i];
    float di = dinv[i];
    int c0 = lane * 2;
    float ax = 0.f, ay = 0.f;
    int mm = m < 64 ? m : 64;
    int sl = 0; float dl = 0.f;
    if (lane < mm) { sl = csr[base + lane]; dl = dinv[sl]; }
    int e = 0;
    for (; e + 3 < mm; e += 4) {   // 4 independent gathers in flight
        int s0 = __shfl(sl, e),     s1 = __shfl(sl, e + 1);
        int s2 = __shfl(sl, e + 2), s3 = __shfl(sl, e + 3);
        float d0 = __shfl(dl, e),     d1 = __shfl(dl, e + 1);
        float d2 = __shfl(dl, e + 2), d3 = __shfl(dl, e + 3);
        half2v h0 = *(const half2v*)(H + (size_t)s0 * FEAT + c0);
        half2v h1 = *(const half2v*)(H + (size_t)s1 * FEAT + c0);
        half2v h2 = *(const half2v*)(H + (size_t)s2 * FEAT + c0);
        half2v h3 = *(const half2v*)(H + (size_t)s3 * FEAT + c0);
        ax += d0 * (float)h0[0] + d1 * (float)h1[0] + d2 * (float)h2[0] + d3 * (float)h3[0];
        ay += d0 * (float)h0[1] + d1 * (float)h1[1] + d2 * (float)h2[1] + d3 * (float)h3[1];
    }
    for (; e < mm; ++e) {
        int s0 = __shfl(sl, e); float d0 = __shfl(dl, e);
        half2v h0 = *(const half2v*)(H + (size_t)s0 * FEAT + c0);
        ax += d0 * (float)h0[0];
        ay += d0 * (float)h0[1];
    }
    for (; e < m; ++e) {  // degree > 64 fallback (rare)
        int s0 = csr[base + e]; float d0 = dinv[s0];
        half2v h0 = *(const half2v*)(H + (size_t)s0 * FEAT + c0);
        ax += d0 * (float)h0[0];
        ay += d0 * (float)h0[1];
    }
    {   // self loop
        half2v hs = *(const half2v*)(H + (size_t)i * FEAT + c0);
        ax += di * (float)hs[0];
        ay += di * (float)hs[1];
    }
    float x0 = di * ax + b1[c0];     x0 = x0 > 0.f ? x0 : 0.f;
    float x1 = di * ay + b1[c0 + 1]; x1 = x1 > 0.f ? x1 : 0.f;
    float y0 = x0 * W2[c0 * 3 + 0] + x1 * W2[c0 * 3 + 3];
    float y1 = x0 * W2[c0 * 3 + 1] + x1 * W2[c0 * 3 + 4];
    float y2 = x0 * W2[c0 * 3 + 2] + x1 * W2[c0 * 3 + 5];
#pragma unroll
    for (int d = 1; d < 64; d <<= 1) {
        y0 += __shfl_xor(y0, d);
        y1 += __shfl_xor(y1, d);
        y2 += __shfl_xor(y2, d);
    }
    if (lane == 0) {
        float* yp = Y + (size_t)i * 4;
        yp[0] = y0; yp[1] = y1; yp[2] = y2;
    }
}

// agg2: thread per node, 3 channels, Y stride 4
__global__ void k_agg2(const float* __restrict__ Y, const int* __restrict__ csr,
                       const int* __restrict__ off, const int* __restrict__ cnt,
                       const float* __restrict__ dinv, const float* __restrict__ b2,
                       float* __restrict__ out, int n) {
    int i = blockIdx.x * 256 + threadIdx.x;
    if (i >= n) return;
    int base = off[i], m = cnt[i];
    float di = dinv[i];
    const float4* Y4 = (const float4*)Y;
    float4 self = Y4[i];
    float a0 = di * self.x, a1 = di * self.y, a2 = di * self.z;
    int e = 0;
    for (; e + 1 < m; e += 2) {
        int s0 = csr[base + e], s1 = csr[base + e + 1];
        float d0 = dinv[s0], d1 = dinv[s1];
        float4 v0 = Y4[s0], v1 = Y4[s1];
        a0 += d0 * v0.x + d1 * v1.x;
        a1 += d0 * v0.y + d1 * v1.y;
        a2 += d0 * v0.z + d1 * v1.z;
    }
    if (e < m) {
        int s0 = csr[base + e]; float d0 = dinv[s0]; float4 v0 = Y4[s0];
        a0 += d0 * v0.x; a1 += d0 * v0.y; a2 += d0 * v0.z;
    }
    out[(size_t)i * 3 + 0] = di * a0 + b2[0];
    out[(size_t)i * 3 + 1] = di * a1 + b2[1];
    out[(size_t)i * 3 + 2] = di * a2 + b2[2];
}

extern "C" void kernel_launch(void* const* d_in, const int* in_sizes, int n_in,
                              void* d_out, int out_size, void* d_ws, size_t ws_size,
                              hipStream_t stream) {
    const float* features = (const float*)d_in[0];
    const int* edges2 = (const int*)d_in[2];   // int64 in reference -> int32 on device
    const float* W1 = (const float*)d_in[5];
    const float* b1 = (const float*)d_in[6];
    const float* W2 = (const float*)d_in[7];
    const float* b2 = (const float*)d_in[8];
    float* out = (float*)d_out;

    const int N = N_NODES, E = N_EDGES;
    const int* srcp = edges2;
    const int* dstp = edges2 + E;

    char* p = (char*)d_ws;
    auto carve = [&](size_t bytes) { char* q = p; p += (bytes + 255) & ~(size_t)255; return q; };
    int* cnt      = (int*)carve(4 * (size_t)N);
    int* off      = (int*)carve(4 * (size_t)N);
    int* cursor   = (int*)carve(4 * (size_t)N);
    int* bsum     = (int*)carve(4 * 128);
    int* bsum2    = (int*)carve(4 * 128);
    int* csr      = (int*)carve(4 * (size_t)E);
    float* dinv   = (float*)carve(4 * (size_t)N);
    _Float16* W1t = (_Float16*)carve(2 * (size_t)IN_CH * FEAT);
    _Float16* H   = (_Float16*)carve(2 * (size_t)N * FEAT);
    float* Y      = (float*)carve(16 * (size_t)N);

    int nb = (N + 1023) / 1024;  // 98

    k_init<<<dim3(512), dim3(256), 0, stream>>>(W1, W1t, cnt);
    k_count<<<dim3((E / 4 + 255) / 256), dim3(256), 0, stream>>>((const int4*)dstp, cnt, E / 4);
    k_scanA<<<dim3(nb), dim3(256), 0, stream>>>(cnt, off, bsum, N);
    k_scanB<<<dim3(1), dim3(128), 0, stream>>>(bsum, bsum2, nb);
    k_scanC<<<dim3(nb), dim3(256), 0, stream>>>(off, bsum2, cnt, cursor, dinv, N);
    k_fill<<<dim3((E / 4 + 255) / 256), dim3(256), 0, stream>>>((const int4*)srcp, (const int4*)dstp, cursor, csr, E / 4);
    k_gemm1<<<dim3((N + 127) / 128), dim3(256), 0, stream>>>(features, W1t, H, N);
    k_agg1<<<dim3((N + 3) / 4), dim3(256), 0, stream>>>(H, csr, off, cnt, dinv, b1, W2, Y, N);
    k_agg2<<<dim3((N + 255) / 256), dim3(256), 0, stream>>>(Y, csr, off, cnt, dinv, b2, out, N);
}